// Round 1
// baseline (8145.101 us; speedup 1.0000x reference)
//
#include <hip/hip_runtime.h>
#include <math.h>

#define DMODEL 2048
#define NHEADS 16
#define DK     128
#define BATCH  4
#define SEQ    2048
#define MROWS  (BATCH*SEQ)   // 8192

// ---------------------------------------------------------------------------
// NT-GEMM tile core: C[m,n] = sum_k X[m,k] * W[n,k]
// X: [*,2048] row-major, W: [2048,2048] row-major. BM=BN=128, BK=16,
// 256 threads, 8x8 micro-tile, waves arranged as 8x8 lanes (2-way LDS
// conflicts only => free on gfx950 per m136).
// ---------------------------------------------------------------------------
__device__ __forceinline__ void gemm_tile_nt(const float* __restrict__ X,
                                             const float* __restrict__ W,
                                             int bm, int bn,
                                             float (&c)[8][8]) {
    __shared__ float As[16][132];   // [k][m], pad 132 (16B-aligned rows)
    __shared__ float Bs[16][132];   // [k][n]

    const int t    = threadIdx.x;
    const int r0   = t >> 2;          // 0..63 (tile row for staging)
    const int q4   = (t & 3) * 4;     // k-quad 0,4,8,12
    const int lane = t & 63;
    const int wave = t >> 6;
    const int row0 = (wave >> 1) * 64 + (lane >> 3) * 8;  // 0..120
    const int col0 = (wave & 1)  * 64 + (lane & 7)  * 8;  // 0..120

    const float* Xa = X + (size_t)(bm + r0)      * DMODEL + q4;
    const float* Xb = X + (size_t)(bm + r0 + 64) * DMODEL + q4;
    const float* Wa = W + (size_t)(bn + r0)      * DMODEL + q4;
    const float* Wb = W + (size_t)(bn + r0 + 64) * DMODEL + q4;

    for (int kt = 0; kt < DMODEL; kt += 16) {
        const float4 xa = *(const float4*)(Xa + kt);
        const float4 xb = *(const float4*)(Xb + kt);
        const float4 wa = *(const float4*)(Wa + kt);
        const float4 wb = *(const float4*)(Wb + kt);
        __syncthreads();   // previous compute done reading LDS
        As[q4+0][r0] = xa.x; As[q4+1][r0] = xa.y; As[q4+2][r0] = xa.z; As[q4+3][r0] = xa.w;
        As[q4+0][r0+64] = xb.x; As[q4+1][r0+64] = xb.y; As[q4+2][r0+64] = xb.z; As[q4+3][r0+64] = xb.w;
        Bs[q4+0][r0] = wa.x; Bs[q4+1][r0] = wa.y; Bs[q4+2][r0] = wa.z; Bs[q4+3][r0] = wa.w;
        Bs[q4+0][r0+64] = wb.x; Bs[q4+1][r0+64] = wb.y; Bs[q4+2][r0+64] = wb.z; Bs[q4+3][r0+64] = wb.w;
        __syncthreads();
#pragma unroll
        for (int kk = 0; kk < 16; ++kk) {
            const float4 a0 = *(const float4*)&As[kk][row0];
            const float4 a1 = *(const float4*)&As[kk][row0 + 4];
            const float4 b0 = *(const float4*)&Bs[kk][col0];
            const float4 b1 = *(const float4*)&Bs[kk][col0 + 4];
            const float a[8] = {a0.x,a0.y,a0.z,a0.w,a1.x,a1.y,a1.z,a1.w};
            const float b[8] = {b0.x,b0.y,b0.z,b0.w,b1.x,b1.y,b1.z,b1.w};
#pragma unroll
            for (int i = 0; i < 8; ++i)
#pragma unroll
                for (int j = 0; j < 8; ++j)
                    c[i][j] += a[i] * b[j];
        }
    }
}

// QKV projection, fused: blockIdx.x in [0,48): g = x>>4 selects Q/K/V,
// nb = x&15 is the head (128 output cols). Output in [B,H,S,DK] layout.
__global__ __launch_bounds__(256)
void qkv_proj_kernel(const float* __restrict__ x,
                     const float* __restrict__ wq,
                     const float* __restrict__ wk,
                     const float* __restrict__ wv,
                     float* __restrict__ Qb, float* __restrict__ Kb,
                     float* __restrict__ Vb) {
    const int g  = blockIdx.x >> 4;
    const int nb = blockIdx.x & 15;         // head index
    const int bm = blockIdx.y * 128;
    const float* W = (g == 0) ? wq : (g == 1) ? wk : wv;
    float* outb    = (g == 0) ? Qb : (g == 1) ? Kb : Vb;

    float c[8][8] = {};
    gemm_tile_nt(x, W, bm, nb * 128, c);

    const int lane = threadIdx.x & 63;
    const int wave = threadIdx.x >> 6;
    const int row0 = (wave >> 1) * 64 + (lane >> 3) * 8;
    const int col0 = (wave & 1)  * 64 + (lane & 7)  * 8;   // = dk base
#pragma unroll
    for (int i = 0; i < 8; ++i) {
        const int m  = bm + row0 + i;
        const int bb = m >> 11;           // /SEQ
        const int ss = m & 2047;
        float* dst = outb + ((size_t)(bb * NHEADS + nb) * SEQ + ss) * DK + col0;
        *(float4*)(dst)     = make_float4(c[i][0], c[i][1], c[i][2], c[i][3]);
        *(float4*)(dst + 4) = make_float4(c[i][4], c[i][5], c[i][6], c[i][7]);
    }
}

// Output projection: out[m, n] = sum_k A[m,k] * wo[n,k], row-major out.
__global__ __launch_bounds__(256)
void out_proj_kernel(const float* __restrict__ A,
                     const float* __restrict__ wo,
                     float* __restrict__ out) {
    const int bn = blockIdx.x * 128;
    const int bm = blockIdx.y * 128;
    float c[8][8] = {};
    gemm_tile_nt(A, wo, bm, bn, c);

    const int lane = threadIdx.x & 63;
    const int wave = threadIdx.x >> 6;
    const int row0 = (wave >> 1) * 64 + (lane >> 3) * 8;
    const int col0 = (wave & 1)  * 64 + (lane & 7)  * 8;
#pragma unroll
    for (int i = 0; i < 8; ++i) {
        float* dst = out + (size_t)(bm + row0 + i) * DMODEL + bn + col0;
        *(float4*)(dst)     = make_float4(c[i][0], c[i][1], c[i][2], c[i][3]);
        *(float4*)(dst + 4) = make_float4(c[i][4], c[i][5], c[i][6], c[i][7]);
    }
}

// ---------------------------------------------------------------------------
// Flash attention, fp32. Grid: (S/32, B*H). 256 threads.
// Thread t: query ql = t>>3 (32/block), dim-group dg = t&7; thread owns dims
// {dg*4 + 32c + j : c<4, j<4} (interleaved so LDS reads are conflict-free:
// 8 unique float4 addrs spread over all 32 banks).
// ---------------------------------------------------------------------------
__global__ __launch_bounds__(256)
void attn_kernel(const float* __restrict__ Q, const float* __restrict__ Kg,
                 const float* __restrict__ Vg, float* __restrict__ O) {
    __shared__ float Ks[32][128];
    __shared__ float Vs[32][128];

    const int bh = blockIdx.y;           // b*16 + h
    const int q0 = blockIdx.x * 32;
    const int t  = threadIdx.x;
    const int ql = t >> 3;
    const int dg = t & 7;
    const float scale = 0.08838834764831845f;  // 1/sqrt(128)

    const float* Qrow = Q + ((size_t)bh * SEQ + q0 + ql) * DK;
    float4 qr[4];
#pragma unroll
    for (int c = 0; c < 4; ++c) qr[c] = *(const float4*)(Qrow + dg * 4 + c * 32);

    float4 o[4];
#pragma unroll
    for (int c = 0; c < 4; ++c) o[c] = make_float4(0.f, 0.f, 0.f, 0.f);
    float mrun = -1e30f, lrun = 0.f;

    const float* Kbase = Kg + (size_t)bh * SEQ * DK;
    const float* Vbase = Vg + (size_t)bh * SEQ * DK;

    for (int kt = 0; kt < SEQ; kt += 32) {
        __syncthreads();   // previous iteration done reading tiles
#pragma unroll
        for (int r = 0; r < 4; ++r) {
            const int f   = t + 256 * r;      // 0..1023
            const int row = f >> 5;
            const int c4  = f & 31;
            *(float4*)&Ks[row][c4 * 4] = ((const float4*)(Kbase + (size_t)(kt + row) * DK))[c4];
            *(float4*)&Vs[row][c4 * 4] = ((const float4*)(Vbase + (size_t)(kt + row) * DK))[c4];
        }
        __syncthreads();

        float s[32];
#pragma unroll
        for (int k = 0; k < 32; ++k) {
            float acc = 0.f;
#pragma unroll
            for (int c = 0; c < 4; ++c) {
                const float4 kv = *(const float4*)&Ks[k][dg * 4 + c * 32];
                acc += qr[c].x * kv.x + qr[c].y * kv.y + qr[c].z * kv.z + qr[c].w * kv.w;
            }
            acc += __shfl_xor(acc, 1);
            acc += __shfl_xor(acc, 2);
            acc += __shfl_xor(acc, 4);
            s[k] = acc * scale;
        }
        float mt = s[0];
#pragma unroll
        for (int k = 1; k < 32; ++k) mt = fmaxf(mt, s[k]);
        const float mnew = fmaxf(mrun, mt);
        const float corr = __expf(mrun - mnew);
        lrun *= corr;
#pragma unroll
        for (int k = 0; k < 32; ++k) { s[k] = __expf(s[k] - mnew); lrun += s[k]; }
#pragma unroll
        for (int c = 0; c < 4; ++c) {
            o[c].x *= corr; o[c].y *= corr; o[c].z *= corr; o[c].w *= corr;
        }
#pragma unroll
        for (int k = 0; k < 32; ++k) {
            const float p = s[k];
#pragma unroll
            for (int c = 0; c < 4; ++c) {
                const float4 vv = *(const float4*)&Vs[k][dg * 4 + c * 32];
                o[c].x += p * vv.x; o[c].y += p * vv.y;
                o[c].z += p * vv.z; o[c].w += p * vv.w;
            }
        }
        mrun = mnew;
    }

    const float inv = 1.f / lrun;
    const int bb = bh >> 4;
    const int h  = bh & 15;
    const size_t orow = ((size_t)bb * SEQ + q0 + ql) * DMODEL + (size_t)h * DK;
#pragma unroll
    for (int c = 0; c < 4; ++c) {
        const float4 ov = make_float4(o[c].x * inv, o[c].y * inv, o[c].z * inv, o[c].w * inv);
        *(float4*)(O + orow + dg * 4 + c * 32) = ov;
    }
}

extern "C" void kernel_launch(void* const* d_in, const int* in_sizes, int n_in,
                              void* d_out, int out_size, void* d_ws, size_t ws_size,
                              hipStream_t stream) {
    const float* x  = (const float*)d_in[0];
    const float* wq = (const float*)d_in[1];
    const float* wk = (const float*)d_in[2];
    const float* wv = (const float*)d_in[3];
    const float* wo = (const float*)d_in[4];
    float* out = (float*)d_out;
    float* ws  = (float*)d_ws;

    // workspace layout (floats): Q,K,V in [B,H,S,DK]; attnO in [B,S,H*DK]
    // total = 4 * 16.78M floats = 268 MB
    float* Qb = ws;
    float* Kb = ws + (size_t)16777216;
    float* Vb = ws + (size_t)33554432;
    float* Ob = ws + (size_t)50331648;

    dim3 blk(256);
    qkv_proj_kernel<<<dim3(48, 64), blk, 0, stream>>>(x, wq, wk, wv, Qb, Kb, Vb);
    attn_kernel<<<dim3(SEQ / 32, BATCH * NHEADS), blk, 0, stream>>>(Qb, Kb, Vb, Ob);
    out_proj_kernel<<<dim3(16, 64), blk, 0, stream>>>(Ob, wo, out);
}